// Round 7
// baseline (285.080 us; speedup 1.0000x reference)
//
#include <hip/hip_runtime.h>
#include <math.h>

#define D_DIM 32000
#define NV4   8000      // D_DIM / 4
#define BLOCK 256
#define KFULL 31        // full strided iterations; tail = NV4 - 31*BLOCK = 64 lanes
#define NBINS 256

// lattice over y = Xs - max(Xs), interval [-1, -(1/32000)^0.5], W0 = 0.9944098300562505
#define BINW_F   3.8844134767822285e-3f  // W0/256
#define INVBW_F  257.43893f              // 256/W0

typedef float floatx4 __attribute__((ext_vector_type(4)));   // native vec for nontemporal store

// 3-pass streaming kernel: one 256-thread block per row, NO register residency.
// Row re-reads (pass 2, 3) hit L2/L3 (row just fetched; ~256 MB active set == L3),
// so HBM traffic is unchanged while VGPR<=64 buys 8 resident blocks/CU -> enough
// phase diversity to keep HBM busy through every block's compute bubble.
// (Round 4/6 lesson: register residency caps residency at 3 blocks/CU and the
// identical-duration blocks convoy -> 40% HBM idle.)

__global__ void __launch_bounds__(BLOCK, 8)
entmax_nsect_kernel(const float* __restrict__ X, float* __restrict__ out, int n_rows) {
    const int row = blockIdx.x;
    if (row >= n_rows) return;
    const int tid  = threadIdx.x;
    const int lane = tid & 63;
    const int wid  = tid >> 6;

    __shared__ __align__(16) float sC[NBINS];   // count  -> suffix count
    __shared__ __align__(16) float sS[NBINS];   // sum    -> suffix sum
    __shared__ __align__(16) float sQ[NBINS];   // sumsq  -> suffix sumsq
    __shared__ float s_wmax[4];                 // per-wave max partials

    const float4* __restrict__ xrow = reinterpret_cast<const float4*>(X + (size_t)row * D_DIM);
    floatx4* __restrict__ orow      = reinterpret_cast<floatx4*>(out + (size_t)row * D_DIM);

    // zero histogram planes (256 threads, 1 element each)
    sC[tid] = 0.0f; sS[tid] = 0.0f; sQ[tid] = 0.0f;

    // ---- Pass 1: row max (streaming read; the only HBM-miss pass) ----
    float mx = -INFINITY;
#pragma unroll 4
    for (int k = 0; k < KFULL; ++k) {
        const float4 a = xrow[tid + k * BLOCK];
        mx = fmaxf(mx, fmaxf(fmaxf(a.x, a.y), fmaxf(a.z, a.w)));
    }
    if (tid < 64) {
        const float4 a = xrow[tid + KFULL * BLOCK];
        mx = fmaxf(mx, fmaxf(fmaxf(a.x, a.y), fmaxf(a.z, a.w)));
    }
#pragma unroll
    for (int o = 32; o > 0; o >>= 1) mx = fmaxf(mx, __shfl_xor(mx, o));
    if (lane == 0) s_wmax[wid] = mx;
    __syncthreads();                                   // B1

    const float m0 = fmaxf(fmaxf(s_wmax[0], s_wmax[1]), fmaxf(s_wmax[2], s_wmax[3]));
    const float maxXs = 0.5f * m0;                     // scale by alpha-1 = 0.5 (exact)

    // ---- Pass 2: moment histogram over y = 0.5*x - maxXs, candidates y > -1 ----
    // (re-read is L2/L3-hot; moments accumulate EXACT y values, bins only select)
#pragma unroll 4
    for (int k = 0; k < KFULL; ++k) {
        const float4 a = xrow[tid + k * BLOCK];
        const float ys[4] = { fmaf(a.x, 0.5f, -maxXs), fmaf(a.y, 0.5f, -maxXs),
                              fmaf(a.z, 0.5f, -maxXs), fmaf(a.w, 0.5f, -maxXs) };
#pragma unroll
        for (int c = 0; c < 4; ++c) {
            const float y = ys[c];
            if (y > -1.0f) {
                const int b = (int)fminf((y + 1.0f) * INVBW_F, 255.0f);
                atomicAdd(&sC[b], 1.0f);
                atomicAdd(&sS[b], y);
                atomicAdd(&sQ[b], y * y);
            }
        }
    }
    if (tid < 64) {
        const float4 a = xrow[tid + KFULL * BLOCK];
        const float ys[4] = { fmaf(a.x, 0.5f, -maxXs), fmaf(a.y, 0.5f, -maxXs),
                              fmaf(a.z, 0.5f, -maxXs), fmaf(a.w, 0.5f, -maxXs) };
#pragma unroll
        for (int c = 0; c < 4; ++c) {
            const float y = ys[c];
            if (y > -1.0f) {
                const int b = (int)fminf((y + 1.0f) * INVBW_F, 255.0f);
                atomicAdd(&sC[b], 1.0f);
                atomicAdd(&sS[b], y);
                atomicAdd(&sQ[b], y * y);
            }
        }
    }
    __syncthreads();                                   // B2

    // ---- Suffix scan (sum over bins >= k), one wave per moment plane ----
    if (wid < 3) {
        float* plane = (wid == 0) ? sC : (wid == 1) ? sS : sQ;
        const float4 f = reinterpret_cast<const float4*>(plane)[lane];
        const float t3 = f.w;
        const float t2 = f.z + t3;
        const float t1 = f.y + t2;
        const float t0 = f.x + t1;
        float inc = t0;                                // inclusive suffix of lane totals
#pragma unroll
        for (int o = 1; o < 64; o <<= 1) {
            const float u = __shfl_down(inc, o);
            if (lane + o < 64) inc += u;
        }
        const float above = inc - t0;                  // exclusive suffix from higher lanes
        float4 o4;
        o4.x = t0 + above; o4.y = t1 + above; o4.z = t2 + above; o4.w = t3 + above;
        reinterpret_cast<float4*>(plane)[lane] = o4;
    }
    __syncthreads();                                   // B3

    // ---- Binary search for the root bin of f(t) = Q - 2tS + t^2 C = 1 ----
    // (f monotone decreasing; f(t_0) >= 1 since the max element contributes 1)
    int klo = 0, khi = 256;
#pragma unroll
    for (int it = 0; it < 8; ++it) {
        const int mid = (klo + khi) >> 1;
        const float t  = fmaf((float)mid, BINW_F, -1.0f);
        const float fm = fmaf(t, fmaf(t, sC[mid], -2.0f * sS[mid]), sQ[mid]);
        if (fm >= 1.0f) klo = mid; else khi = mid;
    }
    // Exact root within the bin: C*t^2 - 2*S*t + (Q-1) = 0, smaller root.
    // Z = Q - 2 tau S + tau^2 C = 1 by construction -> no normalization pass.
    const float C = sC[klo], S = sS[klo], Q = sQ[klo];
    const float disc = fmaxf(fmaf(S, S, -C * (Q - 1.0f)), 0.0f);
    float tauY = (S - sqrtf(disc)) / C;                // C >= 1 (max element in every suffix)
    tauY = fminf(fmaxf(tauY, -1.0f), 0.0f);
    const float tau = maxXs + tauY;

    // ---- Pass 3: output transform (re-read L3-hot; non-temporal stores) ----
#pragma unroll 4
    for (int k = 0; k < KFULL; ++k) {
        const float4 a = xrow[tid + k * BLOCK];
        float d;
        floatx4 p;
        d = fmaxf(fmaf(a.x, 0.5f, -tau), 0.f); p.x = d * d;
        d = fmaxf(fmaf(a.y, 0.5f, -tau), 0.f); p.y = d * d;
        d = fmaxf(fmaf(a.z, 0.5f, -tau), 0.f); p.z = d * d;
        d = fmaxf(fmaf(a.w, 0.5f, -tau), 0.f); p.w = d * d;
        __builtin_nontemporal_store(p, &orow[tid + k * BLOCK]);
    }
    if (tid < 64) {
        const float4 a = xrow[tid + KFULL * BLOCK];
        float d;
        floatx4 p;
        d = fmaxf(fmaf(a.x, 0.5f, -tau), 0.f); p.x = d * d;
        d = fmaxf(fmaf(a.y, 0.5f, -tau), 0.f); p.y = d * d;
        d = fmaxf(fmaf(a.z, 0.5f, -tau), 0.f); p.z = d * d;
        d = fmaxf(fmaf(a.w, 0.5f, -tau), 0.f); p.w = d * d;
        __builtin_nontemporal_store(p, &orow[tid + KFULL * BLOCK]);
    }
}

extern "C" void kernel_launch(void* const* d_in, const int* in_sizes, int n_in,
                              void* d_out, int out_size, void* d_ws, size_t ws_size,
                              hipStream_t stream) {
    const float* X = (const float*)d_in[0];
    float* out     = (float*)d_out;
    const int n_rows = in_sizes[0] / D_DIM;   // 4096
    entmax_nsect_kernel<<<dim3(n_rows), dim3(BLOCK), 0, stream>>>(X, out, n_rows);
}

// Round 8
// 213.274 us; speedup vs baseline: 1.3367x; 1.3367x over previous
//
#include <hip/hip_runtime.h>
#include <math.h>

#define D_DIM 32000
#define NV4   8000      // D_DIM / 4
#define BLOCK 256
#define KREG  24        // float4 per thread in registers -> 6144 float4
#define LDSFULL 7       // full 256-thread iterations in the LDS slice (1792)
#define LDSV4 1856      // float4 in LDS slice (7*256 + 64 tail) ; 6144+1856 = 8000
#define NBINS 256

// lattice over y = Xs - max(Xs), interval [-1, -(1/32000)^0.5], W0 = 0.9944098300562505
#define BINW_F   3.8844134767822285e-3f  // W0/256
#define INVBW_F  257.43893f              // 256/W0

typedef float floatx4 __attribute__((ext_vector_type(4)));   // native vec for nontemporal store

// Single-read kernel (r6 math) with the row split register/LDS so that FOUR
// 256-thread blocks co-reside per CU (16 waves, 4-way phase diversity).
// r7 proved the memory system sustains ~6 TB/s demand at 8 blocks/CU; r6's
// 3-block register-resident version ran at 5.1 TB/s demand on half the bytes.
// This keeps r6's 1.04 GB demand and buys r7-style diversity:
//   regs: 96 VGPR pinned (asm) ; LDS: 29.7 KB data + 3.1 KB hist = 32.8 KB/block.

__global__ void __launch_bounds__(BLOCK, 4)
entmax_nsect_kernel(const float* __restrict__ X, float* __restrict__ out, int n_rows) {
    const int row = blockIdx.x;
    if (row >= n_rows) return;
    const int tid  = threadIdx.x;
    const int lane = tid & 63;
    const int wid  = tid >> 6;

    __shared__ __align__(16) float4 sData[LDSV4];   // LDS slice of the row (raw x)
    __shared__ __align__(16) float sC[NBINS];       // count  -> suffix count
    __shared__ __align__(16) float sS[NBINS];       // sum    -> suffix sum
    __shared__ __align__(16) float sQ[NBINS];       // sumsq  -> suffix sumsq
    __shared__ float s_wmax[4];                     // per-wave max partials

    const float4* __restrict__ xrow = reinterpret_cast<const float4*>(X + (size_t)row * D_DIM);
    floatx4* __restrict__ orow      = reinterpret_cast<floatx4*>(out + (size_t)row * D_DIM);

    // zero histogram planes (256 threads, 1 element each)
    sC[tid] = 0.0f; sS[tid] = 0.0f; sQ[tid] = 0.0f;

    // ---- Phase 1a: register slice load (single HBM read of these bytes) ----
    float4 v[KREG];
#pragma unroll
    for (int k = 0; k < KREG; ++k)
        v[k] = xrow[tid + k * BLOCK];
    // Pin: forbid rematerialization-by-reload (r1-r5 bug: VGPR_Count=44 proved
    // the "register-resident" row was silently re-read from memory 3x).
#pragma unroll
    for (int k = 0; k < KREG; ++k)
        asm volatile("" : "+v"(v[k].x), "+v"(v[k].y), "+v"(v[k].z), "+v"(v[k].w));

    float mx = -INFINITY;
#pragma unroll
    for (int k = 0; k < KREG; ++k)
        mx = fmaxf(mx, fmaxf(fmaxf(v[k].x, v[k].y), fmaxf(v[k].z, v[k].w)));

    // ---- Phase 1b: LDS slice load (max computed inline before ds_write) ----
#pragma unroll
    for (int k = 0; k < LDSFULL; ++k) {
        const float4 t = xrow[KREG * BLOCK + tid + k * BLOCK];
        mx = fmaxf(mx, fmaxf(fmaxf(t.x, t.y), fmaxf(t.z, t.w)));
        sData[tid + k * BLOCK] = t;
    }
    if (tid < 64) {
        const float4 t = xrow[KREG * BLOCK + LDSFULL * BLOCK + tid];
        mx = fmaxf(mx, fmaxf(fmaxf(t.x, t.y), fmaxf(t.z, t.w)));
        sData[LDSFULL * BLOCK + tid] = t;
    }

    // wave max -> block max
#pragma unroll
    for (int o = 32; o > 0; o >>= 1) mx = fmaxf(mx, __shfl_xor(mx, o));
    if (lane == 0) s_wmax[wid] = mx;
    __syncthreads();                                   // B1 (orders sData writes + hist zero too)

    const float m0 = fmaxf(fmaxf(s_wmax[0], s_wmax[1]), fmaxf(s_wmax[2], s_wmax[3]));
    const float maxXs = 0.5f * m0;                     // scale by alpha-1 = 0.5 (exact)

    // ---- Phase 2: moment histogram over y = 0.5*x - maxXs, candidates y > -1 ----
#pragma unroll
    for (int k = 0; k < KREG; ++k) {
        const float ys[4] = { fmaf(v[k].x, 0.5f, -maxXs), fmaf(v[k].y, 0.5f, -maxXs),
                              fmaf(v[k].z, 0.5f, -maxXs), fmaf(v[k].w, 0.5f, -maxXs) };
#pragma unroll
        for (int c = 0; c < 4; ++c) {
            const float y = ys[c];
            if (y > -1.0f) {
                const int b = (int)fminf((y + 1.0f) * INVBW_F, 255.0f);
                atomicAdd(&sC[b], 1.0f);
                atomicAdd(&sS[b], y);
                atomicAdd(&sQ[b], y * y);
            }
        }
    }
#pragma unroll
    for (int k = 0; k < LDSFULL; ++k) {
        const float4 a = sData[tid + k * BLOCK];
        const float ys[4] = { fmaf(a.x, 0.5f, -maxXs), fmaf(a.y, 0.5f, -maxXs),
                              fmaf(a.z, 0.5f, -maxXs), fmaf(a.w, 0.5f, -maxXs) };
#pragma unroll
        for (int c = 0; c < 4; ++c) {
            const float y = ys[c];
            if (y > -1.0f) {
                const int b = (int)fminf((y + 1.0f) * INVBW_F, 255.0f);
                atomicAdd(&sC[b], 1.0f);
                atomicAdd(&sS[b], y);
                atomicAdd(&sQ[b], y * y);
            }
        }
    }
    if (tid < 64) {
        const float4 a = sData[LDSFULL * BLOCK + tid];
        const float ys[4] = { fmaf(a.x, 0.5f, -maxXs), fmaf(a.y, 0.5f, -maxXs),
                              fmaf(a.z, 0.5f, -maxXs), fmaf(a.w, 0.5f, -maxXs) };
#pragma unroll
        for (int c = 0; c < 4; ++c) {
            const float y = ys[c];
            if (y > -1.0f) {
                const int b = (int)fminf((y + 1.0f) * INVBW_F, 255.0f);
                atomicAdd(&sC[b], 1.0f);
                atomicAdd(&sS[b], y);
                atomicAdd(&sQ[b], y * y);
            }
        }
    }
    __syncthreads();                                   // B2

    // ---- Suffix scan (sum over bins >= k), one wave per moment plane ----
    if (wid < 3) {
        float* plane = (wid == 0) ? sC : (wid == 1) ? sS : sQ;
        const float4 f = reinterpret_cast<const float4*>(plane)[lane];
        const float t3 = f.w;
        const float t2 = f.z + t3;
        const float t1 = f.y + t2;
        const float t0 = f.x + t1;
        float inc = t0;                                // inclusive suffix of lane totals
#pragma unroll
        for (int o = 1; o < 64; o <<= 1) {
            const float u = __shfl_down(inc, o);
            if (lane + o < 64) inc += u;
        }
        const float above = inc - t0;                  // exclusive suffix from higher lanes
        float4 o4;
        o4.x = t0 + above; o4.y = t1 + above; o4.z = t2 + above; o4.w = t3 + above;
        reinterpret_cast<float4*>(plane)[lane] = o4;
    }
    __syncthreads();                                   // B3

    // ---- Binary search for the root bin of f(t) = Q - 2tS + t^2 C = 1 ----
    int klo = 0, khi = 256;
#pragma unroll
    for (int it = 0; it < 8; ++it) {
        const int mid = (klo + khi) >> 1;
        const float t  = fmaf((float)mid, BINW_F, -1.0f);
        const float fm = fmaf(t, fmaf(t, sC[mid], -2.0f * sS[mid]), sQ[mid]);
        if (fm >= 1.0f) klo = mid; else khi = mid;
    }
    // Exact root within the bin; Z = 1 by construction -> no normalization pass.
    const float C = sC[klo], S = sS[klo], Q = sQ[klo];
    const float disc = fmaxf(fmaf(S, S, -C * (Q - 1.0f)), 0.0f);
    float tauY = (S - sqrtf(disc)) / C;                // C >= 1 (max element in every suffix)
    tauY = fminf(fmaxf(tauY, -1.0f), 0.0f);
    const float tau = maxXs + tauY;

    // ---- Phase 3: output (register slice, then LDS slice; non-temporal) ----
#pragma unroll
    for (int k = 0; k < KREG; ++k) {
        float d;
        floatx4 p;
        d = fmaxf(fmaf(v[k].x, 0.5f, -tau), 0.f); p.x = d * d;
        d = fmaxf(fmaf(v[k].y, 0.5f, -tau), 0.f); p.y = d * d;
        d = fmaxf(fmaf(v[k].z, 0.5f, -tau), 0.f); p.z = d * d;
        d = fmaxf(fmaf(v[k].w, 0.5f, -tau), 0.f); p.w = d * d;
        __builtin_nontemporal_store(p, &orow[tid + k * BLOCK]);
    }
#pragma unroll
    for (int k = 0; k < LDSFULL; ++k) {
        const float4 a = sData[tid + k * BLOCK];
        float d;
        floatx4 p;
        d = fmaxf(fmaf(a.x, 0.5f, -tau), 0.f); p.x = d * d;
        d = fmaxf(fmaf(a.y, 0.5f, -tau), 0.f); p.y = d * d;
        d = fmaxf(fmaf(a.z, 0.5f, -tau), 0.f); p.z = d * d;
        d = fmaxf(fmaf(a.w, 0.5f, -tau), 0.f); p.w = d * d;
        __builtin_nontemporal_store(p, &orow[KREG * BLOCK + tid + k * BLOCK]);
    }
    if (tid < 64) {
        const float4 a = sData[LDSFULL * BLOCK + tid];
        float d;
        floatx4 p;
        d = fmaxf(fmaf(a.x, 0.5f, -tau), 0.f); p.x = d * d;
        d = fmaxf(fmaf(a.y, 0.5f, -tau), 0.f); p.y = d * d;
        d = fmaxf(fmaf(a.z, 0.5f, -tau), 0.f); p.z = d * d;
        d = fmaxf(fmaf(a.w, 0.5f, -tau), 0.f); p.w = d * d;
        __builtin_nontemporal_store(p, &orow[KREG * BLOCK + LDSFULL * BLOCK + tid]);
    }
}

extern "C" void kernel_launch(void* const* d_in, const int* in_sizes, int n_in,
                              void* d_out, int out_size, void* d_ws, size_t ws_size,
                              hipStream_t stream) {
    const float* X = (const float*)d_in[0];
    float* out     = (float*)d_out;
    const int n_rows = in_sizes[0] / D_DIM;   // 4096
    entmax_nsect_kernel<<<dim3(n_rows), dim3(BLOCK), 0, stream>>>(X, out, n_rows);
}

// Round 9
// 207.853 us; speedup vs baseline: 1.3715x; 1.0261x over previous
//
#include <hip/hip_runtime.h>
#include <math.h>

#define D_DIM 32000
#define NV4   8000      // D_DIM / 4
#define BLOCK 1024
#define KREG  8         // float4 per thread (tid + k*1024 < 8000; k=7 only tid<832)
#define RPB   16        // rows per persistent block
#define NBINS 224       // keeps total LDS <= 131072 B

// lattice over y = Xs - max(Xs), interval [-1, -(1/32000)^0.5], W0 = 0.9944098300562505
#define BINW_F   4.4393297e-3f           // W0/224
#define INVBW_F  225.259277f             // 224/W0

typedef float floatx4 __attribute__((ext_vector_type(4)));   // native vec for nontemporal store
typedef const __attribute__((address_space(1))) uint32_t kGlobU32;
typedef __attribute__((address_space(3)))        uint32_t kLdsU32;

// async global->LDS DMA, 16 B per lane. LDS dest = wave-uniform base + lane*16.
__device__ __forceinline__ void gld_lds16(const float4* g, float4* l) {
    __builtin_amdgcn_global_load_lds((kGlobU32*)g, (kLdsU32*)l, 16, 0, 0);
}

// lgkm-only barrier: LDS ordering without draining vmcnt — async prefetch and
// nontemporal stores stay in flight across it (__syncthreads would vmcnt(0)).
__device__ __forceinline__ void barrier_lds() {
    asm volatile("s_waitcnt lgkmcnt(0)" ::: "memory");
    __builtin_amdgcn_s_barrier();
    asm volatile("" ::: "memory");
}

// issue DMA for one full row into sBuf (wave w owns v4 [w*512, w*512+512); wave 15
// stops at 8000 -> 5 chunks). Per chunk: per-lane global addr, uniform LDS base.
__device__ __forceinline__ void prefetch_row(const float4* __restrict__ xrow,
                                             float4* sBuf, int wid, int lane) {
    const int nch   = (wid == 15) ? 5 : 8;
    const int base0 = wid * 512;
#pragma unroll
    for (int k = 0; k < 8; ++k) {
        if (k < nch) {
            const int base = base0 + (k << 6);
            gld_lds16(xrow + base + lane, sBuf + base);
        }
    }
}

// Persistent kernel: 1 block/CU (LDS-capped), 16 rows each. Row i computed from
// asm-pinned registers while row i+1 streams into LDS via global_load_lds.
// Demand bytes stay at the 1.05 GB floor (single read, single write); the async
// pipeline keeps ~256 KB/CU/row of memory traffic outstanding continuously.

__global__ void __launch_bounds__(BLOCK, 4)
entmax_nsect_kernel(const float* __restrict__ X, float* __restrict__ out, int n_rows) {
    const int tid  = threadIdx.x;
    const int lane = tid & 63;
    const int wid  = tid >> 6;
    const int row0 = blockIdx.x * RPB;

    __shared__ __align__(16) float4 sBuf[NV4 + 16];   // row buffer + 16-float4 tail slack
    __shared__ __align__(16) float  sC[NBINS];        // count  -> suffix count
    __shared__ __align__(16) float  sS[NBINS];        // sum    -> suffix sum
    __shared__ __align__(16) float  sQ[NBINS];        // sumsq  -> suffix sumsq
    float* s_wmax = reinterpret_cast<float*>(&sBuf[NV4]);   // 16 wave-max partials (DMA never writes here)

    if (row0 < n_rows)
        prefetch_row(reinterpret_cast<const float4*>(X + (size_t)row0 * D_DIM), sBuf, wid, lane);

#pragma unroll 1
    for (int i = 0; i < RPB; ++i) {
        const int row = row0 + i;
        if (row >= n_rows) break;                      // block-uniform

        __syncthreads();   // sync#1: vmcnt(0)+lgkmcnt(0)+barrier — prefetch(i) and stores(i-1) complete

        // ---- copy phase: LDS -> regs, pin, zero hist planes, wave max ----
        float4 v[KREG];
#pragma unroll
        for (int k = 0; k < KREG - 1; ++k) v[k] = sBuf[tid + k * BLOCK];
        v[KREG - 1] = (tid < NV4 - (KREG - 1) * BLOCK)
                          ? sBuf[tid + (KREG - 1) * BLOCK]
                          : make_float4(-INFINITY, -INFINITY, -INFINITY, -INFINITY);
#pragma unroll
        for (int k = 0; k < KREG; ++k)
            asm volatile("" : "+v"(v[k].x), "+v"(v[k].y), "+v"(v[k].z), "+v"(v[k].w));

        if (tid < NBINS) { sC[tid] = 0.0f; sS[tid] = 0.0f; sQ[tid] = 0.0f; }

        float mx = -INFINITY;
#pragma unroll
        for (int k = 0; k < KREG; ++k)
            mx = fmaxf(mx, fmaxf(fmaxf(v[k].x, v[k].y), fmaxf(v[k].z, v[k].w)));
#pragma unroll
        for (int o = 32; o > 0; o >>= 1) mx = fmaxf(mx, __shfl_xor(mx, o));
        if (lane == 0) s_wmax[wid] = mx;

        __syncthreads();   // sync#2: no vmem outstanding here — cheap full barrier

        // ---- issue next row's DMA: drains under all compute below ----
        if (row + 1 < n_rows && i + 1 < RPB)
            prefetch_row(reinterpret_cast<const float4*>(X + (size_t)(row + 1) * D_DIM),
                         sBuf, wid, lane);

        // redundant block max from 16 partials
        float m0 = s_wmax[0];
#pragma unroll
        for (int w = 1; w < 16; ++w) m0 = fmaxf(m0, s_wmax[w]);
        const float maxXs = 0.5f * m0;                 // scale by alpha-1 = 0.5 (exact)

        // ---- moment histogram over y = 0.5*x - maxXs, candidates y > -1 ----
#pragma unroll
        for (int k = 0; k < KREG; ++k) {
            const float ys[4] = { fmaf(v[k].x, 0.5f, -maxXs), fmaf(v[k].y, 0.5f, -maxXs),
                                  fmaf(v[k].z, 0.5f, -maxXs), fmaf(v[k].w, 0.5f, -maxXs) };
#pragma unroll
            for (int c = 0; c < 4; ++c) {
                const float y = ys[c];
                if (y > -1.0f) {
                    const int b = (int)fminf((y + 1.0f) * INVBW_F, (float)(NBINS - 1));
                    atomicAdd(&sC[b], 1.0f);
                    atomicAdd(&sS[b], y);
                    atomicAdd(&sQ[b], y * y);
                }
            }
        }
        barrier_lds();                                 // B-hist (lgkm only — DMA stays in flight)

        // ---- suffix scan (sum over bins >= k), one wave per moment plane ----
        if (wid < 3) {
            float* plane = (wid == 0) ? sC : (wid == 1) ? sS : sQ;
            float4 f = make_float4(0.f, 0.f, 0.f, 0.f);
            if (lane < NBINS / 4) f = reinterpret_cast<const float4*>(plane)[lane];
            const float t3 = f.w;
            const float t2 = f.z + t3;
            const float t1 = f.y + t2;
            const float t0 = f.x + t1;
            float inc = t0;
#pragma unroll
            for (int o = 1; o < 64; o <<= 1) {
                const float u = __shfl_down(inc, o);
                if (lane + o < 64) inc += u;
            }
            const float above = inc - t0;
            if (lane < NBINS / 4) {
                float4 o4;
                o4.x = t0 + above; o4.y = t1 + above; o4.z = t2 + above; o4.w = t3 + above;
                reinterpret_cast<float4*>(plane)[lane] = o4;
            }
        }
        barrier_lds();                                 // B-scan

        // ---- binary search for root bin of f(t) = Q - 2tS + t^2 C = 1 ----
        int klo = 0, khi = NBINS;
#pragma unroll
        for (int it = 0; it < 8; ++it) {
            const int mid = (klo + khi) >> 1;
            const float t  = fmaf((float)mid, BINW_F, -1.0f);
            const float fm = fmaf(t, fmaf(t, sC[mid], -2.0f * sS[mid]), sQ[mid]);
            if (fm >= 1.0f) klo = mid; else khi = mid;
        }
        // exact in-bin root; Z = 1 by construction -> no normalization pass
        const float C = sC[klo], S = sS[klo], Q = sQ[klo];
        const float disc = fmaxf(fmaf(S, S, -C * (Q - 1.0f)), 0.0f);
        float tauY = (S - sqrtf(disc)) / C;            // C >= 1 (max element in every suffix)
        tauY = fminf(fmaxf(tauY, -1.0f), 0.0f);
        const float tau = maxXs + tauY;

        // ---- output from registers (non-temporal; fire-and-forget) ----
        floatx4* __restrict__ orow = reinterpret_cast<floatx4*>(out + (size_t)row * D_DIM);
#pragma unroll
        for (int k = 0; k < KREG; ++k) {
            const int j = tid + k * BLOCK;
            if (j < NV4) {
                float d;
                floatx4 p;
                d = fmaxf(fmaf(v[k].x, 0.5f, -tau), 0.f); p.x = d * d;
                d = fmaxf(fmaf(v[k].y, 0.5f, -tau), 0.f); p.y = d * d;
                d = fmaxf(fmaf(v[k].z, 0.5f, -tau), 0.f); p.z = d * d;
                d = fmaxf(fmaf(v[k].w, 0.5f, -tau), 0.f); p.w = d * d;
                __builtin_nontemporal_store(p, &orow[j]);
            }
        }
        // loop -> sync#1 drains stores(i) + prefetch(i+1)
    }
}

extern "C" void kernel_launch(void* const* d_in, const int* in_sizes, int n_in,
                              void* d_out, int out_size, void* d_ws, size_t ws_size,
                              hipStream_t stream) {
    const float* X = (const float*)d_in[0];
    float* out     = (float*)d_out;
    const int n_rows = in_sizes[0] / D_DIM;            // 4096
    const int grid   = (n_rows + RPB - 1) / RPB;       // 256 persistent blocks (1/CU)
    entmax_nsect_kernel<<<dim3(grid), dim3(BLOCK), 0, stream>>>(X, out, n_rows);
}